// Round 3
// baseline (127.181 us; speedup 1.0000x reference)
//
#include <hip/hip_runtime.h>

#define HW 4096      // 64*64 pixels per image
#define NC 256       // C_in
#define ND 256       // C_out

typedef _Float16 half4_t __attribute__((ext_vector_type(4)));
typedef _Float16 half8_t __attribute__((ext_vector_type(8)));
typedef float floatx2 __attribute__((ext_vector_type(2)));
typedef float floatx4 __attribute__((ext_vector_type(4)));

#define MSCALE 64.0f                 // M scaled by 2^6 -> P by 2^12 (keeps f16 normal)
#define INV_MSCALE2 (1.0f / 4096.0f)

// ---------------------------------------------------------------------------
// prep: pack A-operand fragment streams, K-chunk-major so each ks-chunk is a
// contiguous 16KB block:  addr = ((ks*16 + rt)*64 + l)*8 + j
//   W1: rk = rt*16 + (l&15) -> r=rt, k=l&15 ; c = ks*32 + (l>>4)*8 + j
//   W2: d  = rt*16 + (l&15) ; eg = ks*32 + (l>>4)*8 + j
// ---------------------------------------------------------------------------
__global__ __launch_bounds__(256) void prep_weights(
        const float* __restrict__ w_core, const float* __restrict__ w_out,
        _Float16* __restrict__ W1p, _Float16* __restrict__ W2p) {
    int tid = blockIdx.x * 256 + threadIdx.x;   // 16384 threads
    int l   = tid & 63;
    int rt  = (tid >> 6) & 15;
    int ks  = (tid >> 10) & 7;
    int sel = tid >> 13;
    int row = l & 15, kg = l >> 4;
    half8_t v;
    if (sel == 0) {
        int r = rt, k = row;
#pragma unroll
        for (int j = 0; j < 8; ++j) {
            int c = ks * 32 + kg * 8 + j;
            v[j] = (_Float16)(w_core[r * 4096 + c * 16 + k] * MSCALE);
        }
        *(half8_t*)&W1p[(size_t)((ks * 16 + rt) * 64 + l) * 8] = v;
    } else {
        int d = rt * 16 + row;
#pragma unroll
        for (int j = 0; j < 8; ++j) {
            int eg = ks * 32 + kg * 8 + j, e = eg >> 4, g = eg & 15;
            v[j] = (_Float16)w_out[g * 4096 + d * 16 + e];
        }
        *(half8_t*)&W2p[(size_t)((ks * 16 + rt) * 64 + l) * 8] = v;
    }
}

// ---------------------------------------------------------------------------
// Fused: M = W1T.x -> P = M*M -> yT = W2T.P, + partial instance-norm stats.
// 64 pixels/block, 4 waves. LDS 64KB (2 blocks/CU), phase-reused:
//   R1: MT[64][256] f16 (A-out/B-in)      -> W2 K-chunk double-buffer (C)
//   R2: W1 K-chunk double-buffer (A)      -> PL[64][256] f16 (B-out/C-in)
//                                          -> y-tile f32 [128][64] swz (C-out)
// ---------------------------------------------------------------------------
__global__ __launch_bounds__(256, 2) void compute_y(
        const float* __restrict__ x, const _Float16* __restrict__ W1p,
        const _Float16* __restrict__ W2p, float* __restrict__ y,
        float* __restrict__ ssum, float* __restrict__ ssq) {
    __shared__ ushort R1[16384];   // 32KB
    __shared__ ushort R2[16384];   // 32KB

    const int t = threadIdx.x;
    const int l = t & 63, w = t >> 6;
    const int a = blockIdx.x >> 6;
    const int pixbase = (blockIdx.x & 63) * 64;
    const int row16 = l & 15, kg = l >> 4;
    const int lpix = w * 16 + row16;
    const int wpix = pixbase + lpix;
    const int psw  = lpix & 7;
    const float* xa = x + (size_t)a * NC * HW;

    // ---- x B-fragments: 64 coalesced dword loads per thread ----
    half8_t bx[8];
#pragma unroll
    for (int ks = 0; ks < 8; ++ks)
#pragma unroll
        for (int j = 0; j < 8; ++j)
            bx[ks][j] = (_Float16)xa[(size_t)(ks * 32 + kg * 8 + j) * HW + wpix];

    // ---- stage A: MT[rk][pix] via MFMA, W1 chunks double-buffered in R2 ----
    {
        const float4* W1v4 = (const float4*)W1p;   // 1024 float4 per 16KB chunk
        float4* wbuf = (float4*)R2;
        float4 st[4];
#pragma unroll
        for (int q = 0; q < 4; ++q) st[q] = W1v4[q * 256 + t];
#pragma unroll
        for (int q = 0; q < 4; ++q) wbuf[q * 256 + t] = st[q];

        floatx4 acc[16];
#pragma unroll
        for (int i = 0; i < 16; ++i) acc[i] = (floatx4){0.f, 0.f, 0.f, 0.f};

        for (int ks = 0; ks < 8; ++ks) {
            if (ks < 7) {
#pragma unroll
                for (int q = 0; q < 4; ++q)
                    st[q] = W1v4[(ks + 1) * 1024 + q * 256 + t];
            }
            __syncthreads();
            const half8_t* af = (const half8_t*)R2 + (ks & 1) * 1024;
#pragma unroll
            for (int rt = 0; rt < 16; ++rt)
                acc[rt] = __builtin_amdgcn_mfma_f32_16x16x32_f16(
                              af[rt * 64 + l], bx[ks], acc[rt], 0, 0, 0);
            if (ks < 7) {
#pragma unroll
                for (int q = 0; q < 4; ++q)
                    wbuf[((ks + 1) & 1) * 1024 + q * 256 + t] = st[q];
            }
        }
        // MT write: D col=pix(l&15), row rk = rt*16 + kg*4 + r2
#pragma unroll
        for (int rt = 0; rt < 16; ++rt) {
            int rk4 = rt * 4 + kg;
            half4_t hv;
#pragma unroll
            for (int r2 = 0; r2 < 4; ++r2) hv[r2] = (_Float16)acc[rt][r2];
            *(half4_t*)&R1[lpix * 256 + ((rk4 ^ psw) << 2)] = hv;
        }
    }
    __syncthreads();

    // ---- stage B: per-pixel P = M*M (4 threads/pixel), packed f32 FMA ----
    {
        const int p = t >> 2, qe = t & 3, pswb = p & 7;
        float Af[4][16];
#pragma unroll
        for (int i = 0; i < 4; ++i) {
            int e = qe * 4 + i;
#pragma unroll
            for (int f4 = 0; f4 < 4; ++f4) {
                half4_t v = *(const half4_t*)&R1[p * 256 + (((e * 4 + f4) ^ pswb) << 2)];
#pragma unroll
                for (int j = 0; j < 4; ++j) Af[i][f4 * 4 + j] = (float)v[j];
            }
        }
        floatx2 Pacc[4][8];
#pragma unroll
        for (int i = 0; i < 4; ++i)
#pragma unroll
            for (int g2 = 0; g2 < 8; ++g2) Pacc[i][g2] = (floatx2){0.f, 0.f};
#pragma unroll
        for (int f = 0; f < 16; ++f) {
            floatx2 Bg[8];
#pragma unroll
            for (int g4 = 0; g4 < 4; ++g4) {
                half4_t v = *(const half4_t*)&R1[p * 256 + (((f * 4 + g4) ^ pswb) << 2)];
                Bg[g4 * 2]     = (floatx2){(float)v[0], (float)v[1]};
                Bg[g4 * 2 + 1] = (floatx2){(float)v[2], (float)v[3]};
            }
#pragma unroll
            for (int i = 0; i < 4; ++i) {
                floatx2 a2 = {Af[i][f], Af[i][f]};
#pragma unroll
                for (int g2 = 0; g2 < 8; ++g2)
                    Pacc[i][g2] = __builtin_elementwise_fma(a2, Bg[g2], Pacc[i][g2]);
            }
        }
        __syncthreads();   // all MT reads done; R2 (W1 dbuf) also fully consumed
        // PL[pix][eg] f16, 8-elem-unit swizzle, into R2
#pragma unroll
        for (int i = 0; i < 4; ++i) {
            int e = qe * 4 + i;
#pragma unroll
            for (int h2 = 0; h2 < 2; ++h2) {
                half8_t hv;
#pragma unroll
                for (int j = 0; j < 8; ++j)
                    hv[j] = (_Float16)Pacc[i][h2 * 4 + (j >> 1)][j & 1];
                *(half8_t*)&R2[p * 256 + (((e * 2 + h2) ^ pswb) << 3)] = hv;
            }
        }
    }
    __syncthreads();

    // ---- stage C: yT[d][pix] via MFMA, W2 chunks double-buffered in R1 ----
    half8_t pb[8];
#pragma unroll
    for (int ks = 0; ks < 8; ++ks)
        pb[ks] = *(const half8_t*)&R2[lpix * 256 + (((ks * 4 + kg) ^ psw) << 3)];

    floatx4 cacc[16];
#pragma unroll
    for (int i = 0; i < 16; ++i) cacc[i] = (floatx4){0.f, 0.f, 0.f, 0.f};
    {
        const float4* W2v4 = (const float4*)W2p;
        float4* wbuf = (float4*)R1;
        float4 st[4];
#pragma unroll
        for (int q = 0; q < 4; ++q) st[q] = W2v4[q * 256 + t];
        __syncthreads();               // everyone's pb loaded; R1 reads done
#pragma unroll
        for (int q = 0; q < 4; ++q) wbuf[q * 256 + t] = st[q];

        for (int ks = 0; ks < 8; ++ks) {
            if (ks < 7) {
#pragma unroll
                for (int q = 0; q < 4; ++q)
                    st[q] = W2v4[(ks + 1) * 1024 + q * 256 + t];
            }
            __syncthreads();
            const half8_t* af = (const half8_t*)R1 + (ks & 1) * 1024;
#pragma unroll
            for (int dt = 0; dt < 16; ++dt)
                cacc[dt] = __builtin_amdgcn_mfma_f32_16x16x32_f16(
                               af[dt * 64 + l], pb[ks], cacc[dt], 0, 0, 0);
            if (ks < 7) {
#pragma unroll
                for (int q = 0; q < 4; ++q)
                    wbuf[((ks + 1) & 1) * 1024 + q * 256 + t] = st[q];
            }
        }
    }

    // ---- y-tile transpose in LDS (swizzled), coalesced store + stats ----
    float* Yt = (float*)R2;            // [128][64] f32, col-group XOR swizzle
    for (int h = 0; h < 2; ++h) {
        __syncthreads();
#pragma unroll
        for (int dt = h * 8; dt < h * 8 + 8; ++dt) {
            int ddb = (dt - h * 8) * 16 + kg * 4;
#pragma unroll
            for (int r2 = 0; r2 < 4; ++r2) {
                int dd = ddb + r2;
                Yt[dd * 64 + ((((lpix >> 2) ^ dd) & 15) << 2) + (lpix & 3)] =
                    cacc[dt][r2] * INV_MSCALE2;
            }
        }
        __syncthreads();
        const int dd = t >> 1, half = t & 1;
        float s = 0.f, sq = 0.f;
        float* grow = y + (size_t)a * ND * HW + (size_t)(h * 128 + dd) * HW
                        + pixbase + half * 32;
#pragma unroll
        for (int q = 0; q < 8; ++q) {
            int group = half * 8 + q;
            float4 v = *(float4*)&Yt[dd * 64 + (((group ^ dd) & 15) << 2)];
            *(float4*)&grow[q * 4] = v;
            s  += v.x + v.y + v.z + v.w;
            sq += v.x * v.x + v.y * v.y + v.z * v.z + v.w * v.w;
        }
        s  += __shfl_xor(s, 1);
        sq += __shfl_xor(sq, 1);
        if (half == 0) {
            int ad = a * 256 + h * 128 + dd;
            atomicAdd(&ssum[ad], s);
            atomicAdd(&ssq[ad], sq);
        }
    }
}

// ---------------------------------------------------------------------------
__global__ __launch_bounds__(256) void stats_finalize(
        const float* __restrict__ ssum, const float* __restrict__ ssq,
        float* __restrict__ mean_o, float* __restrict__ istd_o) {
    int i = blockIdx.x * 256 + threadIdx.x;   // 4096
    float m = ssum[i] * (1.f / HW);
    float v = ssq[i] * (1.f / HW) - m * m;
    mean_o[i] = m;
    istd_o[i] = rsqrtf(v + 1e-5f);
}

// ---------------------------------------------------------------------------
__global__ __launch_bounds__(256) void finalize_kernel(
        float* __restrict__ y, const float* __restrict__ mean_a,
        const float* __restrict__ istd_a) {
    const int i4 = blockIdx.x * 256 + threadIdx.x;   // float4 index
    const int ad = i4 >> 10;                          // 1024 float4 per (a,d)
    const float m = mean_a[ad], s = istd_a[ad];
    float4 v = ((const float4*)y)[i4];
    float vv[4] = {v.x, v.y, v.z, v.w};
#pragma unroll
    for (int lq = 0; lq < 4; ++lq) {
        float z = (vv[lq] - m) * s;
        vv[lq] = z / (1.f + fabsf(z));
    }
    ((float4*)y)[i4] = make_float4(vv[0], vv[1], vv[2], vv[3]);
}

// ---------------------------------------------------------------------------
extern "C" void kernel_launch(void* const* d_in, const int* in_sizes, int n_in,
                              void* d_out, int out_size, void* d_ws, size_t ws_size,
                              hipStream_t stream) {
    const float* x      = (const float*)d_in[0];
    const float* w_core = (const float*)d_in[1];
    const float* w_out  = (const float*)d_in[2];
    float* y = (float*)d_out;                 // y computed in-place in d_out

    _Float16* W1p = (_Float16*)d_ws;          // 128KB
    _Float16* W2p = W1p + 65536;              // 128KB
    float* ssum   = (float*)(W2p + 65536);    // 4096 f32
    float* ssq    = ssum + 4096;              // 4096 f32
    float* mean_a = ssq + 4096;               // 4096 f32
    float* istd_a = mean_a + 4096;            // 4096 f32  (total 320KB)

    hipMemsetAsync(ssum, 0, 2 * 4096 * sizeof(float), stream);
    prep_weights<<<64, 256, 0, stream>>>(w_core, w_out, W1p, W2p);
    compute_y<<<1024, 256, 0, stream>>>(x, W1p, W2p, y, ssum, ssq);
    stats_finalize<<<16, 256, 0, stream>>>(ssum, ssq, mean_a, istd_a);
    finalize_kernel<<<16384, 256, 0, stream>>>(y, mean_a, istd_a);
}

// Round 4
// 83.906 us; speedup vs baseline: 1.5158x; 1.5158x over previous
//
#include <hip/hip_runtime.h>

#define HW 4096      // 64*64 pixels per image
#define NC 256       // C_in
#define ND 256       // C_out

typedef _Float16 half4_t __attribute__((ext_vector_type(4)));
typedef _Float16 half8_t __attribute__((ext_vector_type(8)));
typedef float floatx2 __attribute__((ext_vector_type(2)));
typedef float floatx4 __attribute__((ext_vector_type(4)));

#define MSCALE 64.0f                 // M scaled by 2^6 -> P by 2^12 (keeps f16 normal)
#define INV_MSCALE2 (1.0f / 4096.0f)

// ---------------------------------------------------------------------------
// prep: pack A-operand fragment streams, K-chunk-major:
//   addr = ((ks*16 + rt)*64 + l)*8 + j
//   W1: rk = rt*16 + (l&15) -> r=rt, k=l&15 ; c = ks*32 + (l>>4)*8 + j
//   W2: d  = rt*16 + (l&15) ; eg = ks*32 + (l>>4)*8 + j
// ---------------------------------------------------------------------------
__global__ __launch_bounds__(256) void prep_weights(
        const float* __restrict__ w_core, const float* __restrict__ w_out,
        _Float16* __restrict__ W1p, _Float16* __restrict__ W2p) {
    int tid = blockIdx.x * 256 + threadIdx.x;   // 16384 threads
    int l   = tid & 63;
    int rt  = (tid >> 6) & 15;
    int ks  = (tid >> 10) & 7;
    int sel = tid >> 13;
    int row = l & 15, kg = l >> 4;
    half8_t v;
    if (sel == 0) {
        int r = rt, k = row;
#pragma unroll
        for (int j = 0; j < 8; ++j) {
            int c = ks * 32 + kg * 8 + j;
            v[j] = (_Float16)(w_core[r * 4096 + c * 16 + k] * MSCALE);
        }
        *(half8_t*)&W1p[(size_t)((ks * 16 + rt) * 64 + l) * 8] = v;
    } else {
        int d = rt * 16 + row;
#pragma unroll
        for (int j = 0; j < 8; ++j) {
            int eg = ks * 32 + kg * 8 + j, e = eg >> 4, g = eg & 15;
            v[j] = (_Float16)w_out[g * 4096 + d * 16 + e];
        }
        *(half8_t*)&W2p[(size_t)((ks * 16 + rt) * 64 + l) * 8] = v;
    }
}

// ---------------------------------------------------------------------------
// Fused: M = W1T.x -> P = M*M -> yT = W2T.P, + partial instance-norm stats.
// 64 px/block, 4 waves. Wave w owns rt/dt tiles {4w..4w+3} x ALL 4 pixel
// tiles -> each weight A-fragment (1KB, from L2) feeds 4 MFMAs in registers;
// weights are read exactly ONCE per block. B-fragments come from LDS tiles.
// Only 3 barriers in the whole kernel.
// LDS (64KB, 2 blocks/CU):  R1: XT[64px][256c] f16 swz -> PL[64px][256eg]
//                           R2: MT[64px][256rk] f16 swz
// ---------------------------------------------------------------------------
__global__ __launch_bounds__(256, 2) void compute_y(
        const float* __restrict__ x, const _Float16* __restrict__ W1p,
        const _Float16* __restrict__ W2p, float* __restrict__ y,
        float* __restrict__ ssum, float* __restrict__ ssq) {
    __shared__ __align__(16) _Float16 R1[16384];   // 32KB
    __shared__ __align__(16) _Float16 R2[16384];   // 32KB

    const int t = threadIdx.x;
    const int l = t & 63, w = t >> 6;
    const int a = blockIdx.x >> 6;
    const int pixbase = (blockIdx.x & 63) * 64;
    const int row16 = l & 15, kg = l >> 4;
    const float* xa = x + (size_t)a * NC * HW + pixbase;

    // ---- cooperative x load -> XT[px][c] f16, 16B-unit XOR swizzle ----
    {
        const int cl  = t >> 4;          // c within 16-row group
        const int pxq = (t & 15) * 4;    // 4 consecutive px per thread
#pragma unroll
        for (int q = 0; q < 16; ++q) {
            int c = q * 16 + cl;
            float4 v = *(const float4*)&xa[(size_t)c * HW + pxq];
            int cu = c >> 3, cr = c & 7;
            float vv[4] = {v.x, v.y, v.z, v.w};
#pragma unroll
            for (int i = 0; i < 4; ++i) {
                int px = pxq + i;
                R1[px * 256 + (cu ^ (px & 15)) * 8 + cr] = (_Float16)vv[i];
            }
        }
    }
    __syncthreads();                                    // (1)

    // ---- stage A: MT = W1T . x  (wave owns rt = 4w..4w+3, all 4 ptiles) ----
    floatx4 acc[4][4];
#pragma unroll
    for (int i = 0; i < 4; ++i)
#pragma unroll
        for (int j = 0; j < 4; ++j) acc[i][j] = (floatx4){0.f, 0.f, 0.f, 0.f};
    {
        const half8_t* W1v = (const half8_t*)W1p;
        for (int ks = 0; ks < 8; ++ks) {
            half8_t af[4];
#pragma unroll
            for (int rq = 0; rq < 4; ++rq)
                af[rq] = W1v[(ks * 16 + w * 4 + rq) * 64 + l];
#pragma unroll
            for (int pt = 0; pt < 4; ++pt) {
                const int px = pt * 16 + row16;
                half8_t bf = *(const half8_t*)
                    &R1[px * 256 + (((ks * 4 + kg) ^ row16) << 3)];
#pragma unroll
                for (int rq = 0; rq < 4; ++rq)
                    acc[rq][pt] = __builtin_amdgcn_mfma_f32_16x16x32_f16(
                                      af[rq], bf, acc[rq][pt], 0, 0, 0);
            }
        }
    }
    // MT write: D col=px(l&15 within ptile), row rk = rt*16 + kg*4 + r2
#pragma unroll
    for (int rq = 0; rq < 4; ++rq) {
        const int rk4 = (w * 4 + rq) * 4 + kg;          // half4 unit 0..63
#pragma unroll
        for (int pt = 0; pt < 4; ++pt) {
            const int px = pt * 16 + row16;
            half4_t hv;
#pragma unroll
            for (int r2 = 0; r2 < 4; ++r2) hv[r2] = (_Float16)acc[rq][pt][r2];
            *(half4_t*)&R2[px * 256 + ((rk4 ^ row16) << 2)] = hv;
        }
    }
    __syncthreads();                                    // (2)

    // ---- stage B: per-pixel P = M*M (4 threads/pixel), packed f32 FMA ----
    {
        const int p = t >> 2, qe = t & 3, ps = p & 15;
        const _Float16* Mp = &R2[p * 256];
        float Af[4][16];
#pragma unroll
        for (int i = 0; i < 4; ++i) {
#pragma unroll
            for (int f4 = 0; f4 < 4; ++f4) {
                half4_t v = *(const half4_t*)
                    &Mp[((((qe * 4 + i) * 4 + f4) ^ ps) << 2)];
#pragma unroll
                for (int j = 0; j < 4; ++j) Af[i][f4 * 4 + j] = (float)v[j];
            }
        }
        floatx2 Pacc[4][8];
#pragma unroll
        for (int i = 0; i < 4; ++i)
#pragma unroll
            for (int g2 = 0; g2 < 8; ++g2) Pacc[i][g2] = (floatx2){0.f, 0.f};
#pragma unroll
        for (int f = 0; f < 16; ++f) {
            floatx2 Bg[8];
#pragma unroll
            for (int g4 = 0; g4 < 4; ++g4) {
                half4_t v = *(const half4_t*)
                    &Mp[(((f * 4 + g4) ^ ps) << 2)];
                Bg[g4 * 2]     = (floatx2){(float)v[0], (float)v[1]};
                Bg[g4 * 2 + 1] = (floatx2){(float)v[2], (float)v[3]};
            }
#pragma unroll
            for (int i = 0; i < 4; ++i) {
                floatx2 a2 = {Af[i][f], Af[i][f]};
#pragma unroll
                for (int g2 = 0; g2 < 8; ++g2)
                    Pacc[i][g2] = __builtin_elementwise_fma(a2, Bg[g2], Pacc[i][g2]);
            }
        }
        // PL[px][eg] f16 (half8 units, 4-bit XOR swizzle) into R1 (XT is dead)
#pragma unroll
        for (int i = 0; i < 4; ++i) {
            const int e = qe * 4 + i;
#pragma unroll
            for (int h2 = 0; h2 < 2; ++h2) {
                half8_t hv;
#pragma unroll
                for (int j = 0; j < 8; ++j)
                    hv[j] = (_Float16)Pacc[i][h2 * 4 + (j >> 1)][j & 1];
                *(half8_t*)&R1[p * 256 + (((e * 2 + h2) ^ ps) << 3)] = hv;
            }
        }
    }
    __syncthreads();                                    // (3)

    // ---- stage C: yT = W2T . P  (wave owns dt = 4w..4w+3, all 4 ptiles) ----
    floatx4 cacc[4][4];
#pragma unroll
    for (int i = 0; i < 4; ++i)
#pragma unroll
        for (int j = 0; j < 4; ++j) cacc[i][j] = (floatx4){0.f, 0.f, 0.f, 0.f};
    {
        const half8_t* W2v = (const half8_t*)W2p;
        for (int ks = 0; ks < 8; ++ks) {
            half8_t af[4];
#pragma unroll
            for (int dq = 0; dq < 4; ++dq)
                af[dq] = W2v[(ks * 16 + w * 4 + dq) * 64 + l];
#pragma unroll
            for (int pt = 0; pt < 4; ++pt) {
                const int px = pt * 16 + row16;
                half8_t bf = *(const half8_t*)
                    &R1[px * 256 + (((ks * 4 + kg) ^ row16) << 3)];
#pragma unroll
                for (int dq = 0; dq < 4; ++dq)
                    cacc[dq][pt] = __builtin_amdgcn_mfma_f32_16x16x32_f16(
                                       af[dq], bf, cacc[dq][pt], 0, 0, 0);
            }
        }
    }

    // ---- epilogue: direct coalesced-64B stores + shuffle-reduced stats ----
    float* ya = y + (size_t)a * ND * HW + pixbase;
#pragma unroll
    for (int dq = 0; dq < 4; ++dq) {
        const int dbase = (w * 4 + dq) * 16 + kg * 4;
#pragma unroll
        for (int r2 = 0; r2 < 4; ++r2) {
            const int d = dbase + r2;
            float s = 0.f, q2 = 0.f;
#pragma unroll
            for (int pt = 0; pt < 4; ++pt) {
                float v = cacc[dq][pt][r2] * INV_MSCALE2;
                ya[(size_t)d * HW + pt * 16 + row16] = v;
                s += v; q2 += v * v;
            }
#pragma unroll
            for (int off = 1; off < 16; off <<= 1) {
                s  += __shfl_xor(s, off);
                q2 += __shfl_xor(q2, off);
            }
            if (row16 == 0) {
                atomicAdd(&ssum[a * 256 + d], s);
                atomicAdd(&ssq [a * 256 + d], q2);
            }
        }
    }
}

// ---------------------------------------------------------------------------
__global__ __launch_bounds__(256) void stats_finalize(
        const float* __restrict__ ssum, const float* __restrict__ ssq,
        float* __restrict__ mean_o, float* __restrict__ istd_o) {
    int i = blockIdx.x * 256 + threadIdx.x;   // 4096
    float m = ssum[i] * (1.f / HW);
    float v = ssq[i] * (1.f / HW) - m * m;
    mean_o[i] = m;
    istd_o[i] = rsqrtf(v + 1e-5f);
}

// ---------------------------------------------------------------------------
__global__ __launch_bounds__(256) void finalize_kernel(
        float* __restrict__ y, const float* __restrict__ mean_a,
        const float* __restrict__ istd_a) {
    const int i4 = blockIdx.x * 256 + threadIdx.x;   // float4 index
    const int ad = i4 >> 10;                          // 1024 float4 per (a,d)
    const float m = mean_a[ad], s = istd_a[ad];
    float4 v = ((const float4*)y)[i4];
    float vv[4] = {v.x, v.y, v.z, v.w};
#pragma unroll
    for (int lq = 0; lq < 4; ++lq) {
        float z = (vv[lq] - m) * s;
        vv[lq] = z / (1.f + fabsf(z));
    }
    ((float4*)y)[i4] = make_float4(vv[0], vv[1], vv[2], vv[3]);
}

// ---------------------------------------------------------------------------
extern "C" void kernel_launch(void* const* d_in, const int* in_sizes, int n_in,
                              void* d_out, int out_size, void* d_ws, size_t ws_size,
                              hipStream_t stream) {
    const float* x      = (const float*)d_in[0];
    const float* w_core = (const float*)d_in[1];
    const float* w_out  = (const float*)d_in[2];
    float* y = (float*)d_out;                 // y computed in-place in d_out

    _Float16* W1p = (_Float16*)d_ws;          // 128KB
    _Float16* W2p = W1p + 65536;              // 128KB
    float* ssum   = (float*)(W2p + 65536);    // 4096 f32
    float* ssq    = ssum + 4096;              // 4096 f32
    float* mean_a = ssq + 4096;               // 4096 f32
    float* istd_a = mean_a + 4096;            // 4096 f32  (total 320KB)

    hipMemsetAsync(ssum, 0, 2 * 4096 * sizeof(float), stream);
    prep_weights<<<64, 256, 0, stream>>>(w_core, w_out, W1p, W2p);
    compute_y<<<1024, 256, 0, stream>>>(x, W1p, W2p, y, ssum, ssq);
    stats_finalize<<<16, 256, 0, stream>>>(ssum, ssq, mean_a, istd_a);
    finalize_kernel<<<16384, 256, 0, stream>>>(y, mean_a, istd_a);
}